// Round 1
// baseline (2606.885 us; speedup 1.0000x reference)
//
#include <hip/hip_runtime.h>
#include <hip/hip_bf16.h>
#include <math.h>

// Problem constants (fixed shapes per reference)
#define Bb   32
#define Tt   1024
#define Dd   512
#define Kk   64
#define K2   128     // 2K
#define Hh   4
#define KP   16
#define MLPD 2048
#define Mrows (Bb * Tt)   // 32768

// Conv window: mag <= sigmoid(-0.1)=0.475; 0.475^48 ~ 3e-16 -> exact to fp32
#define CW 48
#define CT 64

__device__ __forceinline__ float sigf(float x) { return 1.0f / (1.0f + __expf(-x)); }

// ---------------- LayerNorm: one wave (64 lanes) per row of 512 ----------------
__global__ __launch_bounds__(256) void ln_kernel(const float* __restrict__ x,
                                                 const float* __restrict__ g,
                                                 const float* __restrict__ b,
                                                 float* __restrict__ o) {
    int row  = blockIdx.x * 4 + (threadIdx.x >> 6);
    int lane = threadIdx.x & 63;
    const float4* xr = (const float4*)(x + (size_t)row * Dd);
    float4 a = xr[lane];
    float4 c = xr[lane + 64];
    float s = a.x + a.y + a.z + a.w + c.x + c.y + c.z + c.w;
    float q = a.x * a.x + a.y * a.y + a.z * a.z + a.w * a.w
            + c.x * c.x + c.y * c.y + c.z * c.z + c.w * c.w;
#pragma unroll
    for (int m = 32; m > 0; m >>= 1) {
        s += __shfl_xor(s, m);
        q += __shfl_xor(q, m);
    }
    float mean = s * (1.0f / Dd);
    float var  = q * (1.0f / Dd) - mean * mean;
    float rs   = rsqrtf(var + 1e-5f);
    const float4* gg = (const float4*)g;
    const float4* bb = (const float4*)b;
    float4 g0 = gg[lane], g1 = gg[lane + 64];
    float4 b0 = bb[lane], b1 = bb[lane + 64];
    float4* oo = (float4*)(o + (size_t)row * Dd);
    float4 r0, r1;
    r0.x = (a.x - mean) * rs * g0.x + b0.x;
    r0.y = (a.y - mean) * rs * g0.y + b0.y;
    r0.z = (a.z - mean) * rs * g0.z + b0.z;
    r0.w = (a.w - mean) * rs * g0.w + b0.w;
    r1.x = (c.x - mean) * rs * g1.x + b1.x;
    r1.y = (c.y - mean) * rs * g1.y + b1.y;
    r1.z = (c.z - mean) * rs * g1.z + b1.z;
    r1.w = (c.w - mean) * rs * g1.w + b1.w;
    oo[lane]      = r0;
    oo[lane + 64] = r1;
}

// ---------------- Kernel table precompute: kern[d][0..63]=real, [64..127]=imag ----
__global__ void kern_precompute(const float* __restrict__ log_decay,
                                const float* __restrict__ freq,
                                float* __restrict__ kern) {
    int i = blockIdx.x * 256 + threadIdx.x;
    if (i >= CW * Kk) return;
    int d = i >> 6, k = i & 63;
    float mag = 1.0f / (1.0f + expf(-log_decay[k]));
    float mp  = powf(mag, (float)d);
    float ph  = (float)d * freq[k];
    kern[d * K2 + k]      = mp * cosf(ph);
    kern[d * K2 + 64 + k] = mp * sinf(ph);
}

// ---------------- Windowed causal complex conv + per-head coupling ----------------
// grid (T/CT, B), 256 threads. Writes eigenstates [M,128] (cols 0..63 real, 64..127 imag)
__global__ __launch_bounds__(256) void conv_kernel(const float* __restrict__ beta,
                                                   const float* __restrict__ kern,
                                                   const float* __restrict__ coup,
                                                   float* __restrict__ eig) {
    __shared__ float sBeta[CT + CW][K2];   // 112*128*4 = 56 KB
    __shared__ float sCoup[Hh][KP][KP];    // transposed: [h][k][j]
    int b   = blockIdx.y;
    int t0  = blockIdx.x * CT;
    int tid = threadIdx.x;
    for (int i = tid; i < Hh * KP * KP; i += 256) {
        int h = i >> 8, j = (i >> 4) & 15, kk = i & 15;
        sCoup[h][kk][j] = coup[i];         // coup[h][j][k] row-major
    }
    for (int i = tid; i < (CT + CW) * K2; i += 256) {
        int r = i >> 7, c = i & 127;
        int t = t0 - CW + r;
        sBeta[r][c] = (t >= 0) ? beta[((size_t)b * Tt + t) * K2 + c] : 0.0f;
    }
    __syncthreads();
    int k  = tid & 63;
    int ts = tid >> 6;                     // 4 t-phases
    float cr[16], ci[16];
#pragma unroll
    for (int i = 0; i < 16; i++) { cr[i] = 0.0f; ci[i] = 0.0f; }
    for (int d = 0; d < CW; d++) {
        float kr = kern[d * K2 + k];
        float ki = kern[d * K2 + 64 + k];
#pragma unroll
        for (int i = 0; i < 16; i++) {
            int r    = CW + ts + 4 * i - d;
            float br = sBeta[r][k];
            float bi = sBeta[r][64 + k];
            cr[i] += kr * br - ki * bi;
            ci[i] += kr * bi + ki * br;
        }
    }
    __syncthreads();
#pragma unroll
    for (int i = 0; i < 16; i++) {
        int tl = ts + 4 * i;
        sBeta[tl][k]      = cr[i];
        sBeta[tl][64 + k] = ci[i];
    }
    __syncthreads();
    int h = k >> 4, jj = k & 15;           // output col j = k = h*16+jj
#pragma unroll
    for (int i = 0; i < 16; i++) {
        int tl = ts + 4 * i;
        float er = 0.0f, ei = 0.0f;
#pragma unroll
        for (int kk = 0; kk < KP; kk++) {
            float w = sCoup[h][kk][jj];
            er += w * sBeta[tl][h * KP + kk];
            ei += w * sBeta[tl][64 + h * KP + kk];
        }
        size_t off = ((size_t)b * Tt + t0 + tl) * K2;
        eig[off + k]      = er;
        eig[off + 64 + k] = ei;
    }
}

// ---------------- Generic tiled SGEMM with fused epilogues ----------------
#define BM 64
#define BN 64
#define BK 16

enum { EPI_NONE = 0, EPI_GATE, EPI_X1, EPI_SILU, EPI_OUT0, EPI_OUTA };

template <int EPI>
__global__ __launch_bounds__(256) void gemm_kernel(
    const float* __restrict__ A, const float* __restrict__ Bmat,
    float* __restrict__ C, int K, int ldb, int ldc,
    const float* __restrict__ bias, const float* __restrict__ aux1,
    const float* __restrict__ aux2) {
    __shared__ float sA[BK][BM + 4];   // +4 pad: keeps float4 align, breaks conflicts
    __shared__ float sB[BK][BN];
    int bm  = blockIdx.y * BM;
    int bn  = blockIdx.x * BN;
    int tid = threadIdx.x;
    int tm  = (tid >> 4) << 2;   // 0..60
    int tn  = (tid & 15) << 2;   // 0..60
    float acc[4][4] = {};
    int ar = tid >> 2;           // 0..63
    int ac = (tid & 3) << 2;     // 0,4,8,12
    int br = tid >> 4;           // 0..15
    int bc = (tid & 15) << 2;    // 0..60
    const float* Aptr = A + (size_t)(bm + ar) * K + ac;
    const float* Bptr = Bmat + (size_t)br * ldb + bn + bc;
    for (int k0 = 0; k0 < K; k0 += BK) {
        float4 av = *(const float4*)(Aptr + k0);
        float4 bv = *(const float4*)(Bptr + (size_t)k0 * ldb);
        sA[ac + 0][ar] = av.x;
        sA[ac + 1][ar] = av.y;
        sA[ac + 2][ar] = av.z;
        sA[ac + 3][ar] = av.w;
        *(float4*)&sB[br][bc] = bv;
        __syncthreads();
#pragma unroll
        for (int kk = 0; kk < BK; kk++) {
            float4 a4 = *(const float4*)&sA[kk][tm];
            float4 b4 = *(const float4*)&sB[kk][tn];
            acc[0][0] += a4.x * b4.x; acc[0][1] += a4.x * b4.y; acc[0][2] += a4.x * b4.z; acc[0][3] += a4.x * b4.w;
            acc[1][0] += a4.y * b4.x; acc[1][1] += a4.y * b4.y; acc[1][2] += a4.y * b4.z; acc[1][3] += a4.y * b4.w;
            acc[2][0] += a4.z * b4.x; acc[2][1] += a4.z * b4.y; acc[2][2] += a4.z * b4.z; acc[2][3] += a4.z * b4.w;
            acc[3][0] += a4.w * b4.x; acc[3][1] += a4.w * b4.y; acc[3][2] += a4.w * b4.z; acc[3][3] += a4.w * b4.w;
        }
        __syncthreads();
    }
#pragma unroll
    for (int i = 0; i < 4; i++) {
        size_t off = (size_t)(bm + tm + i) * ldc + bn + tn;
        float4 v = make_float4(acc[i][0], acc[i][1], acc[i][2], acc[i][3]);
        if (EPI == EPI_NONE) {
            *(float4*)&C[off] = v;
        } else if (EPI == EPI_GATE) {
            const float4 bb = *(const float4*)&bias[bn + tn];
            v.x = sigf(v.x + bb.x); v.y = sigf(v.y + bb.y);
            v.z = sigf(v.z + bb.z); v.w = sigf(v.w + bb.w);
            *(float4*)&C[off] = v;
        } else if (EPI == EPI_X1) {
            const float4 xv = *(const float4*)&aux1[off];
            const float4 gv = *(const float4*)&aux2[off];
            v.x = xv.x + gv.x * v.x; v.y = xv.y + gv.y * v.y;
            v.z = xv.z + gv.z * v.z; v.w = xv.w + gv.w * v.w;
            *(float4*)&C[off] = v;
        } else if (EPI == EPI_SILU) {
            const float4 bb = *(const float4*)&bias[bn + tn];
            float t;
            t = v.x + bb.x; v.x = t * sigf(t);
            t = v.y + bb.y; v.y = t * sigf(t);
            t = v.z + bb.z; v.z = t * sigf(t);
            t = v.w + bb.w; v.w = t * sigf(t);
            *(float4*)&C[off] = v;
        } else if (EPI == EPI_OUT0) {
            const float4 bb = *(const float4*)&bias[bn + tn];
            const float4 xv = *(const float4*)&aux1[off];
            v.x += bb.x + xv.x; v.y += bb.y + xv.y;
            v.z += bb.z + xv.z; v.w += bb.w + xv.w;
            *(float4*)&C[off] = v;
        } else {  // EPI_OUTA: accumulate into C
            const float4 pv = *(const float4*)&C[off];
            v.x += pv.x; v.y += pv.y; v.z += pv.z; v.w += pv.w;
            *(float4*)&C[off] = v;
        }
    }
}

extern "C" void kernel_launch(void* const* d_in, const int* in_sizes, int n_in,
                              void* d_out, int out_size, void* d_ws, size_t ws_size,
                              hipStream_t stream) {
    (void)in_sizes; (void)n_in; (void)out_size;
    const float* x         = (const float*)d_in[0];
    const float* w_in      = (const float*)d_in[1];
    const float* log_decay = (const float*)d_in[2];
    const float* frequency = (const float*)d_in[3];
    const float* coupling  = (const float*)d_in[4];
    const float* w_out     = (const float*)d_in[5];
    const float* w_gate    = (const float*)d_in[6];
    const float* b_gate    = (const float*)d_in[7];
    const float* w1        = (const float*)d_in[8];
    const float* b1        = (const float*)d_in[9];
    const float* w2        = (const float*)d_in[10];
    const float* b2        = (const float*)d_in[11];
    const float* g1        = (const float*)d_in[12];
    const float* bn1       = (const float*)d_in[13];
    const float* g2        = (const float*)d_in[14];
    const float* bn2       = (const float*)d_in[15];

    float* out = (float*)d_out;                        // [32768, 512]
    float* eig = (float*)d_out + (size_t)Mrows * Dd;   // [32768, 128]

    // Workspace layout (bytes):
    //   buf0: xn then x1            [32768,512] @ 0        (64 MB)
    //   buf1: gate then xn2         [32768,512] @ 64 MB    (64 MB)
    //   beta:                       [32768,128] @ 128 MB   (16 MB)
    //   kern table:                 [48,128]    @ 144 MB   (24 KB, padded slot 64 KB)
    //   hid: MLP hidden chunk       [32768,CC]  @ ~144 MB
    char*  ws   = (char*)d_ws;
    float* buf0 = (float*)(ws);
    float* buf1 = (float*)(ws + 67108864ull);
    float* beta = (float*)(ws + 134217728ull);
    float* kern = (float*)(ws + 150994944ull);
    float* hid  = (float*)(ws + 151060480ull);

    // MLP hidden chunk width, adapted to available workspace
    size_t avail = ws_size > 151060480ull ? ws_size - 151060480ull : 0;
    int CC = MLPD;
    while (CC > 64 && (size_t)Mrows * (size_t)CC * 4ull > avail) CC >>= 1;
    int nch = MLPD / CC;

    dim3 blk(256);
    kern_precompute<<<dim3((CW * Kk + 255) / 256), blk, 0, stream>>>(log_decay, frequency, kern);
    ln_kernel<<<dim3(Mrows / 4), blk, 0, stream>>>(x, g1, bn1, buf0);
    // beta = xn @ w_in  [32768,128]
    gemm_kernel<EPI_NONE><<<dim3(K2 / BN, Mrows / BM), blk, 0, stream>>>(
        buf0, w_in, beta, Dd, K2, K2, nullptr, nullptr, nullptr);
    // gate = sigmoid(xn @ w_gate + b_gate)  [32768,512]
    gemm_kernel<EPI_GATE><<<dim3(Dd / BN, Mrows / BM), blk, 0, stream>>>(
        buf0, w_gate, buf1, Dd, Dd, Dd, b_gate, nullptr, nullptr);
    // eigenstates (windowed conv + coupling) -> second output region
    conv_kernel<<<dim3(Tt / CT, Bb), blk, 0, stream>>>(beta, kern, coupling, eig);
    // x1 = x + gate * (eig @ w_out)   (overwrites xn in buf0; xn is dead)
    gemm_kernel<EPI_X1><<<dim3(Dd / BN, Mrows / BM), blk, 0, stream>>>(
        eig, w_out, buf0, K2, Dd, Dd, nullptr, x, buf1);
    // xn2 = LN(x1)  (overwrites gate in buf1; gate is dead)
    ln_kernel<<<dim3(Mrows / 4), blk, 0, stream>>>(buf0, g2, bn2, buf1);
    // MLP chunked over the 2048 dim: out = x1 + b2 + sum_c silu(xn2@w1_c + b1_c)@w2_c
    for (int c = 0; c < nch; c++) {
        gemm_kernel<EPI_SILU><<<dim3(CC / BN, Mrows / BM), blk, 0, stream>>>(
            buf1, w1 + (size_t)c * CC, hid, Dd, MLPD, CC, b1 + (size_t)c * CC, nullptr, nullptr);
        if (c == 0) {
            gemm_kernel<EPI_OUT0><<<dim3(Dd / BN, Mrows / BM), blk, 0, stream>>>(
                hid, w2 + (size_t)c * CC * Dd, out, CC, Dd, Dd, b2, buf0, nullptr);
        } else {
            gemm_kernel<EPI_OUTA><<<dim3(Dd / BN, Mrows / BM), blk, 0, stream>>>(
                hid, w2 + (size_t)c * CC * Dd, out, CC, Dd, Dd, nullptr, nullptr, nullptr);
        }
    }
}

// Round 2
// 624.709 us; speedup vs baseline: 4.1730x; 4.1730x over previous
//
#include <hip/hip_runtime.h>
#include <math.h>
#include <stdint.h>

// Problem constants (fixed shapes per reference)
#define Bb   32
#define Tt   1024
#define Dd   512
#define Kk   64
#define K2   128     // 2K
#define Hh   4
#define KP   16
#define MLPD 2048
#define Mrows (Bb * Tt)   // 32768

// Conv window: mag <= sigmoid(-0.1)=0.475; 0.475^48 ~ 3e-16 -> exact to fp32
#define CW 48
#define CT 64

typedef unsigned short ushort_t;
typedef __attribute__((ext_vector_type(8))) short short8;     // 8 bf16 = 4 VGPRs
typedef __attribute__((ext_vector_type(4))) float floatx4;    // MFMA C/D

__device__ __forceinline__ float sigf(float x) { return 1.0f / (1.0f + __expf(-x)); }

__device__ __forceinline__ ushort_t f2bf(float f) {
    unsigned u = __float_as_uint(f);
    u += 0x7fffu + ((u >> 16) & 1u);   // round-to-nearest-even
    return (ushort_t)(u >> 16);
}
__device__ __forceinline__ float bf2f(ushort_t h) {
    return __uint_as_float(((unsigned)h) << 16);
}

// async global->LDS, 16B per lane. LDS dest is wave-uniform base + lane*16.
__device__ __forceinline__ void async16(const void* g, void* l) {
    __builtin_amdgcn_global_load_lds((const __attribute__((address_space(1))) void*)g,
                                     (__attribute__((address_space(3))) void*)l, 16, 0, 0);
}

// ---------------- LayerNorm: one wave per row of 512, bf16 output ----------------
__global__ __launch_bounds__(256) void ln_bf_kernel(const float* __restrict__ x,
                                                    const float* __restrict__ g,
                                                    const float* __restrict__ b,
                                                    ushort_t* __restrict__ o) {
    int row  = blockIdx.x * 4 + (threadIdx.x >> 6);
    int lane = threadIdx.x & 63;
    const float4* xr = (const float4*)(x + (size_t)row * Dd);
    float4 a = xr[lane];
    float4 c = xr[lane + 64];
    float s = a.x + a.y + a.z + a.w + c.x + c.y + c.z + c.w;
    float q = a.x * a.x + a.y * a.y + a.z * a.z + a.w * a.w
            + c.x * c.x + c.y * c.y + c.z * c.z + c.w * c.w;
#pragma unroll
    for (int m = 32; m > 0; m >>= 1) {
        s += __shfl_xor(s, m);
        q += __shfl_xor(q, m);
    }
    float mean = s * (1.0f / Dd);
    float var  = q * (1.0f / Dd) - mean * mean;
    float rs   = rsqrtf(var + 1e-5f);
    const float4* gg = (const float4*)g;
    const float4* bb = (const float4*)b;
    float4 g0 = gg[lane], g1 = gg[lane + 64];
    float4 b0 = bb[lane], b1 = bb[lane + 64];
    ushort4 r0, r1;
    r0.x = f2bf((a.x - mean) * rs * g0.x + b0.x);
    r0.y = f2bf((a.y - mean) * rs * g0.y + b0.y);
    r0.z = f2bf((a.z - mean) * rs * g0.z + b0.z);
    r0.w = f2bf((a.w - mean) * rs * g0.w + b0.w);
    r1.x = f2bf((c.x - mean) * rs * g1.x + b1.x);
    r1.y = f2bf((c.y - mean) * rs * g1.y + b1.y);
    r1.z = f2bf((c.z - mean) * rs * g1.z + b1.z);
    r1.w = f2bf((c.w - mean) * rs * g1.w + b1.w);
    ushort4* oo = (ushort4*)(o + (size_t)row * Dd);
    oo[lane]      = r0;
    oo[lane + 64] = r1;
}

// ---------------- fp32 [R,C] -> bf16 [C,R] transpose+convert ----------------
__global__ __launch_bounds__(256) void convert_transpose(const float* __restrict__ in,
                                                         ushort_t* __restrict__ out,
                                                         int R, int C) {
    __shared__ float t[32][33];
    int bx = blockIdx.x * 32;   // C offset
    int by = blockIdx.y * 32;   // R offset
    int tc = threadIdx.x & 31, tr = threadIdx.x >> 5;   // 8 rows per pass
#pragma unroll
    for (int i = 0; i < 4; i++)
        t[tr + 8 * i][tc] = in[(size_t)(by + tr + 8 * i) * C + bx + tc];
    __syncthreads();
#pragma unroll
    for (int i = 0; i < 4; i++)
        out[(size_t)(bx + tr + 8 * i) * R + by + tc] = f2bf(t[tc][tr + 8 * i]);
}

// ---------------- Kernel table precompute: kern[d][0..63]=real, [64..127]=imag ----
__global__ void kern_precompute(const float* __restrict__ log_decay,
                                const float* __restrict__ freq,
                                float* __restrict__ kern) {
    int i = blockIdx.x * 256 + threadIdx.x;
    if (i >= CW * Kk) return;
    int d = i >> 6, k = i & 63;
    float mag = 1.0f / (1.0f + expf(-log_decay[k]));
    float mp  = powf(mag, (float)d);
    float ph  = (float)d * freq[k];
    kern[d * K2 + k]      = mp * cosf(ph);
    kern[d * K2 + 64 + k] = mp * sinf(ph);
}

// ---------------- Windowed causal complex conv + per-head coupling ----------------
// grid (T/CT, B). Writes eig fp32 (output) + eigb bf16 (for w_out gemm)
__global__ __launch_bounds__(256) void conv_kernel(const float* __restrict__ beta,
                                                   const float* __restrict__ kern,
                                                   const float* __restrict__ coup,
                                                   float* __restrict__ eig,
                                                   ushort_t* __restrict__ eigb) {
    __shared__ float sBeta[CT + CW][K2];   // 56 KB
    __shared__ float sCoup[Hh][KP][KP];    // transposed: [h][k][j]
    int b   = blockIdx.y;
    int t0  = blockIdx.x * CT;
    int tid = threadIdx.x;
    for (int i = tid; i < Hh * KP * KP; i += 256) {
        int h = i >> 8, j = (i >> 4) & 15, kk = i & 15;
        sCoup[h][kk][j] = coup[i];
    }
    for (int i = tid; i < (CT + CW) * K2; i += 256) {
        int r = i >> 7, c = i & 127;
        int t = t0 - CW + r;
        sBeta[r][c] = (t >= 0) ? beta[((size_t)b * Tt + t) * K2 + c] : 0.0f;
    }
    __syncthreads();
    int k  = tid & 63;
    int ts = tid >> 6;
    float cr[16], ci[16];
#pragma unroll
    for (int i = 0; i < 16; i++) { cr[i] = 0.0f; ci[i] = 0.0f; }
    for (int d = 0; d < CW; d++) {
        float kr = kern[d * K2 + k];
        float ki = kern[d * K2 + 64 + k];
#pragma unroll
        for (int i = 0; i < 16; i++) {
            int r    = CW + ts + 4 * i - d;
            float br = sBeta[r][k];
            float bi = sBeta[r][64 + k];
            cr[i] += kr * br - ki * bi;
            ci[i] += kr * bi + ki * br;
        }
    }
    __syncthreads();
#pragma unroll
    for (int i = 0; i < 16; i++) {
        int tl = ts + 4 * i;
        sBeta[tl][k]      = cr[i];
        sBeta[tl][64 + k] = ci[i];
    }
    __syncthreads();
    int h = k >> 4, jj = k & 15;
#pragma unroll
    for (int i = 0; i < 16; i++) {
        int tl = ts + 4 * i;
        float er = 0.0f, ei = 0.0f;
#pragma unroll
        for (int kk = 0; kk < KP; kk++) {
            float w = sCoup[h][kk][jj];
            er += w * sBeta[tl][h * KP + kk];
            ei += w * sBeta[tl][64 + h * KP + kk];
        }
        size_t off = ((size_t)b * Tt + t0 + tl) * K2;
        eig[off + k]       = er;
        eig[off + 64 + k]  = ei;
        eigb[off + k]      = f2bf(er);
        eigb[off + 64 + k] = f2bf(ei);
    }
}

// ---------------- bf16 MFMA GEMM: C[M,N] = A[M,K] @ Bt[N,K]^T, fused epilogues ----
// 128x128 tile, BK=32, 256 threads (4 waves, each 64x64 = 4x4 of 16x16x32 MFMA).
// LDS physical layout swizzled: colgroup p = (g + (row>>1)) & 3 (swizzle applied on
// the global source address, since global_load_lds writes lane*16 contiguous).
enum { EPI_BETA = 0, EPI_GATE, EPI_X1, EPI_SILU, EPI_OUT0, EPI_OUTA };

template <int EPI>
__global__ __launch_bounds__(256) void mfma_gemm(
    const ushort_t* __restrict__ A, const ushort_t* __restrict__ Bt,
    void* __restrict__ Cv, int K, int ldb, int ldc,
    const float* __restrict__ bias,
    const float* __restrict__ aux1, const ushort_t* __restrict__ aux2) {
    __shared__ __align__(16) char lds[16384];
    char* sA = lds;
    char* sB = lds + 8192;
    int tid  = threadIdx.x;
    int lane = tid & 63, w = tid >> 6;
    int bm = blockIdx.y * 128, bn = blockIdx.x * 128;
    int wm = (w >> 1) * 64, wn = (w & 1) * 64;

    // staging: each wave DMAs 2 A-chunks + 2 B-chunks of 1 KB (64 lanes x 16 B)
    const char* gA[2];
    const char* gB[2];
    char* lA[2];
    char* lB[2];
#pragma unroll
    for (int q = 0; q < 2; q++) {
        int c = 2 * w + q;
        int m = c * 16 + (lane >> 2);                 // tile row this lane feeds
        int g = ((lane & 3) - ((m >> 1) & 3)) & 3;    // logical k-colgroup (swizzle)
        gA[q] = (const char*)(A  + (size_t)(bm + m) * K   + g * 8);
        gB[q] = (const char*)(Bt + (size_t)(bn + m) * ldb + g * 8);
        lA[q] = sA + c * 1024;
        lB[q] = sB + c * 1024;
    }
    // fragment LDS byte offsets (swizzle-aware), fixed across K loop
    int aoff[4], boff[4];
#pragma unroll
    for (int i = 0; i < 4; i++) {
        int m = wm + i * 16 + (lane & 15);
        aoff[i] = m * 64 + ((((lane >> 4) + (m >> 1)) & 3) * 16);
        int n = wn + i * 16 + (lane & 15);
        boff[i] = n * 64 + ((((lane >> 4) + (n >> 1)) & 3) * 16);
    }
    floatx4 acc[4][4];
#pragma unroll
    for (int i = 0; i < 4; i++)
#pragma unroll
        for (int j = 0; j < 4; j++) acc[i][j] = (floatx4)0.0f;

    for (int k0 = 0; k0 < K; k0 += 32) {
        size_t kb = (size_t)k0 * 2;
        async16(gA[0] + kb, lA[0]);
        async16(gA[1] + kb, lA[1]);
        async16(gB[0] + kb, lB[0]);
        async16(gB[1] + kb, lB[1]);
        __syncthreads();
        short8 af[4], bfr[4];
#pragma unroll
        for (int i = 0; i < 4; i++) af[i]  = *(const short8*)(sA + aoff[i]);
#pragma unroll
        for (int j = 0; j < 4; j++) bfr[j] = *(const short8*)(sB + boff[j]);
#pragma unroll
        for (int i = 0; i < 4; i++)
#pragma unroll
            for (int j = 0; j < 4; j++)
                acc[i][j] = __builtin_amdgcn_mfma_f32_16x16x32_bf16(af[i], bfr[j], acc[i][j], 0, 0, 0);
        __syncthreads();
    }
    // epilogue: C/D layout col=lane&15, row=(lane>>4)*4+reg
    int rq = (lane >> 4) * 4;
    int cn = lane & 15;
#pragma unroll
    for (int i = 0; i < 4; i++) {
#pragma unroll
        for (int j = 0; j < 4; j++) {
            int col = bn + wn + j * 16 + cn;
#pragma unroll
            for (int r = 0; r < 4; r++) {
                int row    = bm + wm + i * 16 + rq + r;
                size_t off = (size_t)row * ldc + col;
                float v    = acc[i][j][r];
                if (EPI == EPI_BETA) {
                    ((float*)Cv)[off] = v;
                } else if (EPI == EPI_GATE) {
                    ((ushort_t*)Cv)[off] = f2bf(sigf(v + bias[col]));
                } else if (EPI == EPI_X1) {
                    ((float*)Cv)[off] = aux1[off] + bf2f(aux2[off]) * v;
                } else if (EPI == EPI_SILU) {
                    float t = v + bias[col];
                    ((ushort_t*)Cv)[off] = f2bf(t * sigf(t));
                } else if (EPI == EPI_OUT0) {
                    float* C = (float*)Cv;
                    C[off] = C[off] + v + bias[col];   // C holds x1; adds b2
                } else {  // EPI_OUTA
                    float* C = (float*)Cv;
                    C[off] += v;
                }
            }
        }
    }
}

extern "C" void kernel_launch(void* const* d_in, const int* in_sizes, int n_in,
                              void* d_out, int out_size, void* d_ws, size_t ws_size,
                              hipStream_t stream) {
    (void)in_sizes; (void)n_in; (void)out_size;
    const float* x         = (const float*)d_in[0];
    const float* w_in      = (const float*)d_in[1];
    const float* log_decay = (const float*)d_in[2];
    const float* frequency = (const float*)d_in[3];
    const float* coupling  = (const float*)d_in[4];
    const float* w_out     = (const float*)d_in[5];
    const float* w_gate    = (const float*)d_in[6];
    const float* b_gate    = (const float*)d_in[7];
    const float* w1        = (const float*)d_in[8];
    const float* b1        = (const float*)d_in[9];
    const float* w2        = (const float*)d_in[10];
    const float* b2        = (const float*)d_in[11];
    const float* g1        = (const float*)d_in[12];
    const float* bn1       = (const float*)d_in[13];
    const float* g2        = (const float*)d_in[14];
    const float* bn2       = (const float*)d_in[15];

    float* out = (float*)d_out;                        // [32768,512]; holds x1 then final
    float* eig = (float*)d_out + (size_t)Mrows * Dd;   // [32768,128] fp32 output

    // ws layout (MB offsets)
    char* ws = (char*)d_ws;
    ushort_t* xn     = (ushort_t*)(ws);                     // 32 MB  [M,512] bf16
    ushort_t* xn2    = (ushort_t*)(ws + (32ull  << 20));    // 32 MB
    float*    beta   = (float*)   (ws + (64ull  << 20));    // 16 MB  [M,128] fp32
    ushort_t* eigb   = (ushort_t*)(ws + (80ull  << 20));    //  8 MB  [M,128] bf16
    ushort_t* gateb  = (ushort_t*)(ws + (88ull  << 20));    // 32 MB  [M,512] bf16
    ushort_t* w_inT  = (ushort_t*)(ws + (120ull << 20));    // [128,512]
    ushort_t* w_gateT= (ushort_t*)(ws + (121ull << 20));    // [512,512]
    ushort_t* w_outT = (ushort_t*)(ws + (122ull << 20));    // [512,128]
    ushort_t* w1T    = (ushort_t*)(ws + (123ull << 20));    // [2048,512] (2 MB)
    ushort_t* w2T    = (ushort_t*)(ws + (125ull << 20));    // [512,2048] (2 MB)
    float*    kern   = (float*)   (ws + (127ull << 20));    // 24 KB

    // MLP hidden chunk: prefer tail of ws; else reuse dead xn region (32 MB)
    size_t base = 128ull << 20;
    ushort_t* hid;
    int CC;
    if (ws_size >= base + ((size_t)Mrows * 2048 * 2)) { hid = (ushort_t*)(ws + base); CC = 2048; }
    else if (ws_size >= base + ((size_t)Mrows * 1024 * 2)) { hid = (ushort_t*)(ws + base); CC = 1024; }
    else { hid = (ushort_t*)ws; CC = 512; }   // xn is dead by MLP time
    int nch = MLPD / CC;

    dim3 blk(256);
    // weight transpose+convert (tiny)
    convert_transpose<<<dim3(K2 / 32, Dd / 32), blk, 0, stream>>>(w_in, w_inT, Dd, K2);
    convert_transpose<<<dim3(Dd / 32, Dd / 32), blk, 0, stream>>>(w_gate, w_gateT, Dd, Dd);
    convert_transpose<<<dim3(Dd / 32, K2 / 32), blk, 0, stream>>>(w_out, w_outT, K2, Dd);
    convert_transpose<<<dim3(MLPD / 32, Dd / 32), blk, 0, stream>>>(w1, w1T, Dd, MLPD);
    convert_transpose<<<dim3(Dd / 32, MLPD / 32), blk, 0, stream>>>(w2, w2T, MLPD, Dd);
    kern_precompute<<<dim3((CW * Kk + 255) / 256), blk, 0, stream>>>(log_decay, frequency, kern);

    // xn = LN(x) -> bf16
    ln_bf_kernel<<<dim3(Mrows / 4), blk, 0, stream>>>(x, g1, bn1, xn);
    // beta = xn @ w_in  (fp32 out, feeds conv)
    mfma_gemm<EPI_BETA><<<dim3(K2 / 128, Mrows / 128), blk, 0, stream>>>(
        xn, w_inT, beta, Dd, Dd, K2, nullptr, nullptr, nullptr);
    // gate = sigmoid(xn @ w_gate + b_gate) -> bf16
    mfma_gemm<EPI_GATE><<<dim3(Dd / 128, Mrows / 128), blk, 0, stream>>>(
        xn, w_gateT, gateb, Dd, Dd, Dd, b_gate, nullptr, nullptr);
    // eigenstates: windowed conv + coupling -> eig (fp32 out) + eigb (bf16)
    conv_kernel<<<dim3(Tt / CT, Bb), blk, 0, stream>>>(beta, kern, coupling, eig, eigb);
    // x1 = x + gate * (eig @ w_out)  -> d_out[0:64MB] (in place of final out)
    mfma_gemm<EPI_X1><<<dim3(Dd / 128, Mrows / 128), blk, 0, stream>>>(
        eigb, w_outT, out, K2, K2, Dd, nullptr, x, gateb);
    // xn2 = LN(x1) -> bf16
    ln_bf_kernel<<<dim3(Mrows / 4), blk, 0, stream>>>(out, g2, bn2, xn2);
    // MLP: out = x1 + b2 + sum_c silu(xn2@w1_c + b1_c)@w2_c
    for (int c = 0; c < nch; c++) {
        mfma_gemm<EPI_SILU><<<dim3(CC / 128, Mrows / 128), blk, 0, stream>>>(
            xn2, w1T + (size_t)c * CC * Dd, hid, Dd, Dd, CC, b1 + (size_t)c * CC, nullptr, nullptr);
        if (c == 0) {
            mfma_gemm<EPI_OUT0><<<dim3(Dd / 128, Mrows / 128), blk, 0, stream>>>(
                hid, w2T + (size_t)c * CC, out, CC, MLPD, Dd, b2, nullptr, nullptr);
        } else {
            mfma_gemm<EPI_OUTA><<<dim3(Dd / 128, Mrows / 128), blk, 0, stream>>>(
                hid, w2T + (size_t)c * CC, out, CC, MLPD, Dd, nullptr, nullptr, nullptr);
        }
    }
}

// Round 3
// 592.449 us; speedup vs baseline: 4.4002x; 1.0545x over previous
//
#include <hip/hip_runtime.h>
#include <math.h>
#include <stdint.h>

// Problem constants (fixed shapes per reference)
#define Bb   32
#define Tt   1024
#define Dd   512
#define Kk   64
#define K2   128     // 2K
#define Hh   4
#define KP   16
#define MLPD 2048
#define Mrows (Bb * Tt)   // 32768

// Conv window: mag <= sigmoid(-0.1)=0.475; 0.475^48 ~ 3e-16 -> exact to fp32
#define CW 48
#define CT 64

typedef unsigned short ushort_t;
typedef __attribute__((ext_vector_type(8))) short short8;     // 8 bf16 = 4 VGPRs
typedef __attribute__((ext_vector_type(4))) float floatx4;    // MFMA C/D

__device__ __forceinline__ float sigf(float x) { return 1.0f / (1.0f + __expf(-x)); }

__device__ __forceinline__ ushort_t f2bf(float f) {
    unsigned u = __float_as_uint(f);
    u += 0x7fffu + ((u >> 16) & 1u);   // round-to-nearest-even
    return (ushort_t)(u >> 16);
}
__device__ __forceinline__ float bf2f(ushort_t h) {
    return __uint_as_float(((unsigned)h) << 16);
}

// async global->LDS, 16B per lane. LDS dest is wave-uniform base + lane*16.
__device__ __forceinline__ void async16(const void* g, void* l) {
    __builtin_amdgcn_global_load_lds((const __attribute__((address_space(1))) void*)g,
                                     (__attribute__((address_space(3))) void*)l, 16, 0, 0);
}

// ---------------- LayerNorm: one wave per row of 512, bf16 output ----------------
__global__ __launch_bounds__(256) void ln_bf_kernel(const float* __restrict__ x,
                                                    const float* __restrict__ g,
                                                    const float* __restrict__ b,
                                                    ushort_t* __restrict__ o) {
    int row  = blockIdx.x * 4 + (threadIdx.x >> 6);
    int lane = threadIdx.x & 63;
    const float4* xr = (const float4*)(x + (size_t)row * Dd);
    float4 a = xr[lane];
    float4 c = xr[lane + 64];
    float s = a.x + a.y + a.z + a.w + c.x + c.y + c.z + c.w;
    float q = a.x * a.x + a.y * a.y + a.z * a.z + a.w * a.w
            + c.x * c.x + c.y * c.y + c.z * c.z + c.w * c.w;
#pragma unroll
    for (int m = 32; m > 0; m >>= 1) {
        s += __shfl_xor(s, m);
        q += __shfl_xor(q, m);
    }
    float mean = s * (1.0f / Dd);
    float var  = q * (1.0f / Dd) - mean * mean;
    float rs   = rsqrtf(var + 1e-5f);
    const float4* gg = (const float4*)g;
    const float4* bb = (const float4*)b;
    float4 g0 = gg[lane], g1 = gg[lane + 64];
    float4 b0 = bb[lane], b1 = bb[lane + 64];
    ushort4 r0, r1;
    r0.x = f2bf((a.x - mean) * rs * g0.x + b0.x);
    r0.y = f2bf((a.y - mean) * rs * g0.y + b0.y);
    r0.z = f2bf((a.z - mean) * rs * g0.z + b0.z);
    r0.w = f2bf((a.w - mean) * rs * g0.w + b0.w);
    r1.x = f2bf((c.x - mean) * rs * g1.x + b1.x);
    r1.y = f2bf((c.y - mean) * rs * g1.y + b1.y);
    r1.z = f2bf((c.z - mean) * rs * g1.z + b1.z);
    r1.w = f2bf((c.w - mean) * rs * g1.w + b1.w);
    ushort4* oo = (ushort4*)(o + (size_t)row * Dd);
    oo[lane]      = r0;
    oo[lane + 64] = r1;
}

// ---------------- fp32 [R,C] -> bf16 [C,R] transpose+convert ----------------
__global__ __launch_bounds__(256) void convert_transpose(const float* __restrict__ in,
                                                         ushort_t* __restrict__ out,
                                                         int R, int C) {
    __shared__ float t[32][33];
    int bx = blockIdx.x * 32;   // C offset
    int by = blockIdx.y * 32;   // R offset
    int tc = threadIdx.x & 31, tr = threadIdx.x >> 5;   // 8 rows per pass
#pragma unroll
    for (int i = 0; i < 4; i++)
        t[tr + 8 * i][tc] = in[(size_t)(by + tr + 8 * i) * C + bx + tc];
    __syncthreads();
#pragma unroll
    for (int i = 0; i < 4; i++)
        out[(size_t)(bx + tr + 8 * i) * R + by + tc] = f2bf(t[tc][tr + 8 * i]);
}

// ---------------- Kernel table precompute: kern[d][0..63]=real, [64..127]=imag ----
__global__ void kern_precompute(const float* __restrict__ log_decay,
                                const float* __restrict__ freq,
                                float* __restrict__ kern) {
    int i = blockIdx.x * 256 + threadIdx.x;
    if (i >= CW * Kk) return;
    int d = i >> 6, k = i & 63;
    float mag = 1.0f / (1.0f + expf(-log_decay[k]));
    float mp  = powf(mag, (float)d);
    float ph  = (float)d * freq[k];
    kern[d * K2 + k]      = mp * cosf(ph);
    kern[d * K2 + 64 + k] = mp * sinf(ph);
}

// ---------------- Windowed causal complex conv + per-head coupling ----------------
__global__ __launch_bounds__(256) void conv_kernel(const float* __restrict__ beta,
                                                   const float* __restrict__ kern,
                                                   const float* __restrict__ coup,
                                                   float* __restrict__ eig,
                                                   ushort_t* __restrict__ eigb) {
    __shared__ float sBeta[CT + CW][K2];   // 56 KB
    __shared__ float sCoup[Hh][KP][KP];    // transposed: [h][k][j]
    int b   = blockIdx.y;
    int t0  = blockIdx.x * CT;
    int tid = threadIdx.x;
    for (int i = tid; i < Hh * KP * KP; i += 256) {
        int h = i >> 8, j = (i >> 4) & 15, kk = i & 15;
        sCoup[h][kk][j] = coup[i];
    }
    for (int i = tid; i < (CT + CW) * K2; i += 256) {
        int r = i >> 7, c = i & 127;
        int t = t0 - CW + r;
        sBeta[r][c] = (t >= 0) ? beta[((size_t)b * Tt + t) * K2 + c] : 0.0f;
    }
    __syncthreads();
    int k  = tid & 63;
    int ts = tid >> 6;
    float cr[16], ci[16];
#pragma unroll
    for (int i = 0; i < 16; i++) { cr[i] = 0.0f; ci[i] = 0.0f; }
    for (int d = 0; d < CW; d++) {
        float kr = kern[d * K2 + k];
        float ki = kern[d * K2 + 64 + k];
#pragma unroll
        for (int i = 0; i < 16; i++) {
            int r    = CW + ts + 4 * i - d;
            float br = sBeta[r][k];
            float bi = sBeta[r][64 + k];
            cr[i] += kr * br - ki * bi;
            ci[i] += kr * bi + ki * br;
        }
    }
    __syncthreads();
#pragma unroll
    for (int i = 0; i < 16; i++) {
        int tl = ts + 4 * i;
        sBeta[tl][k]      = cr[i];
        sBeta[tl][64 + k] = ci[i];
    }
    __syncthreads();
    int h = k >> 4, jj = k & 15;
#pragma unroll
    for (int i = 0; i < 16; i++) {
        int tl = ts + 4 * i;
        float er = 0.0f, ei = 0.0f;
#pragma unroll
        for (int kk = 0; kk < KP; kk++) {
            float w = sCoup[h][kk][jj];
            er += w * sBeta[tl][h * KP + kk];
            ei += w * sBeta[tl][64 + h * KP + kk];
        }
        size_t off = ((size_t)b * Tt + t0 + tl) * K2;
        eig[off + k]       = er;
        eig[off + 64 + k]  = ei;
        eigb[off + k]      = f2bf(er);
        eigb[off + 64 + k] = f2bf(ei);
    }
}

// ---------------- bf16 MFMA GEMM, double-buffered async staging ----------------
// 128x128 tile, BK=32, 256 threads (4 waves, each 64x64 = 4x4 of 16x16x32 MFMA).
// LDS: 2 stages x (8 KB A + 8 KB B). Prefetch for step k+1 issued before the
// MFMA block of step k; the compiler's vmcnt(0)-drain before s_barrier then
// waits on a load that compute has already covered.
// Swizzle: colgroup p = (g + (row>>1)) & 3 applied on the global source address.
enum { EPI_INCOMB = 0, EPI_X1, EPI_SILU, EPI_OUT0, EPI_OUTA };

#define STG 16384

template <int EPI>
__global__ __launch_bounds__(256) void mfma_gemm(
    const ushort_t* __restrict__ A, const ushort_t* __restrict__ Bt,
    void* __restrict__ Cv, void* __restrict__ Cv2, int K, int ldb, int ldc,
    const float* __restrict__ bias,
    const float* __restrict__ aux1, const ushort_t* __restrict__ aux2) {
    __shared__ __align__(16) char lds[2 * STG];
    int tid  = threadIdx.x;
    int lane = tid & 63, w = tid >> 6;
    int bm = blockIdx.y * 128, bn = blockIdx.x * 128;
    int wm = (w >> 1) * 64, wn = (w & 1) * 64;

    // staging: each wave DMAs 2 A-chunks + 2 B-chunks of 1 KB (64 lanes x 16 B)
    const char* gA[2];
    const char* gB[2];
    int lofsA[2], lofsB[2];
#pragma unroll
    for (int q = 0; q < 2; q++) {
        int c = 2 * w + q;
        int m = c * 16 + (lane >> 2);                 // tile row this lane feeds
        int g = ((lane & 3) - ((m >> 1) & 3)) & 3;    // logical k-colgroup (swizzle)
        gA[q] = (const char*)(A  + (size_t)(bm + m) * K   + g * 8);
        gB[q] = (const char*)(Bt + (size_t)(bn + m) * ldb + g * 8);
        lofsA[q] = c * 1024;
        lofsB[q] = 8192 + c * 1024;
    }
    // fragment LDS byte offsets (swizzle-aware), fixed across K loop
    int aoff[4], boff[4];
#pragma unroll
    for (int i = 0; i < 4; i++) {
        int m = wm + i * 16 + (lane & 15);
        aoff[i] = m * 64 + ((((lane >> 4) + (m >> 1)) & 3) * 16);
        int n = wn + i * 16 + (lane & 15);
        boff[i] = 8192 + n * 64 + ((((lane >> 4) + (n >> 1)) & 3) * 16);
    }
    floatx4 acc[4][4];
#pragma unroll
    for (int i = 0; i < 4; i++)
#pragma unroll
        for (int j = 0; j < 4; j++) acc[i][j] = (floatx4)0.0f;

    // preload K-step 0 into stage 0
    async16(gA[0], lds + lofsA[0]);
    async16(gA[1], lds + lofsA[1]);
    async16(gB[0], lds + lofsB[0]);
    async16(gB[1], lds + lofsB[1]);
    __syncthreads();

    int p = 0;
    for (int k0 = 0; k0 < K; k0 += 32) {
        if (k0 + 32 < K) {   // prefetch next step into idle stage
            size_t kb = (size_t)(k0 + 32) * 2;
            char* d = lds + (p ^ 1) * STG;
            async16(gA[0] + kb, d + lofsA[0]);
            async16(gA[1] + kb, d + lofsA[1]);
            async16(gB[0] + kb, d + lofsB[0]);
            async16(gB[1] + kb, d + lofsB[1]);
        }
        const char* s = lds + p * STG;
        short8 af[4], bfr[4];
#pragma unroll
        for (int i = 0; i < 4; i++) af[i]  = *(const short8*)(s + aoff[i]);
#pragma unroll
        for (int j = 0; j < 4; j++) bfr[j] = *(const short8*)(s + boff[j]);
#pragma unroll
        for (int i = 0; i < 4; i++)
#pragma unroll
            for (int j = 0; j < 4; j++)
                acc[i][j] = __builtin_amdgcn_mfma_f32_16x16x32_bf16(af[i], bfr[j], acc[i][j], 0, 0, 0);
        __syncthreads();   // drains prefetch vmcnt + protects stage p for refill
        p ^= 1;
    }
    // epilogue: C/D layout col=lane&15, row=(lane>>4)*4+reg
    int rq = (lane >> 4) * 4;
    int cn = lane & 15;
#pragma unroll
    for (int i = 0; i < 4; i++) {
#pragma unroll
        for (int j = 0; j < 4; j++) {
            int col = bn + wn + j * 16 + cn;
#pragma unroll
            for (int r = 0; r < 4; r++) {
                int row    = bm + wm + i * 16 + rq + r;
                float v    = acc[i][j][r];
                if (EPI == EPI_INCOMB) {
                    // cols 0..127 -> beta fp32 [M,128]; cols 128..639 -> gate bf16 [M,512]
                    if (blockIdx.x == 0) {
                        ((float*)Cv)[(size_t)row * K2 + col] = v;
                    } else {
                        int gc = col - 128;
                        ((ushort_t*)Cv2)[(size_t)row * Dd + gc] = f2bf(sigf(v + bias[gc]));
                    }
                } else if (EPI == EPI_X1) {
                    size_t off = (size_t)row * ldc + col;
                    ((float*)Cv)[off] = aux1[off] + bf2f(aux2[off]) * v;
                } else if (EPI == EPI_SILU) {
                    size_t off = (size_t)row * ldc + col;
                    float t = v + bias[col];
                    ((ushort_t*)Cv)[off] = f2bf(t * sigf(t));
                } else if (EPI == EPI_OUT0) {
                    size_t off = (size_t)row * ldc + col;
                    float* C = (float*)Cv;
                    C[off] = C[off] + v + bias[col];   // C holds x1; adds b2
                } else {  // EPI_OUTA
                    size_t off = (size_t)row * ldc + col;
                    ((float*)Cv)[off] += v;
                }
            }
        }
    }
}

extern "C" void kernel_launch(void* const* d_in, const int* in_sizes, int n_in,
                              void* d_out, int out_size, void* d_ws, size_t ws_size,
                              hipStream_t stream) {
    (void)in_sizes; (void)n_in; (void)out_size;
    const float* x         = (const float*)d_in[0];
    const float* w_in      = (const float*)d_in[1];
    const float* log_decay = (const float*)d_in[2];
    const float* frequency = (const float*)d_in[3];
    const float* coupling  = (const float*)d_in[4];
    const float* w_out     = (const float*)d_in[5];
    const float* w_gate    = (const float*)d_in[6];
    const float* b_gate    = (const float*)d_in[7];
    const float* w1        = (const float*)d_in[8];
    const float* b1        = (const float*)d_in[9];
    const float* w2        = (const float*)d_in[10];
    const float* b2        = (const float*)d_in[11];
    const float* g1        = (const float*)d_in[12];
    const float* bn1       = (const float*)d_in[13];
    const float* g2        = (const float*)d_in[14];
    const float* bn2       = (const float*)d_in[15];

    float* out = (float*)d_out;                        // [32768,512]; holds x1 then final
    float* eig = (float*)d_out + (size_t)Mrows * Dd;   // [32768,128] fp32 output

    // ws layout (MB offsets)
    char* ws = (char*)d_ws;
    ushort_t* xn      = (ushort_t*)(ws);                     // 32 MB  [M,512] bf16
    ushort_t* xn2     = (ushort_t*)(ws + (32ull  << 20));    // 32 MB
    float*    beta    = (float*)   (ws + (64ull  << 20));    // 16 MB  [M,128] fp32
    ushort_t* eigb    = (ushort_t*)(ws + (80ull  << 20));    //  8 MB  [M,128] bf16
    ushort_t* gateb   = (ushort_t*)(ws + (88ull  << 20));    // 32 MB  [M,512] bf16
    ushort_t* w_comb  = (ushort_t*)(ws + (120ull << 20));    // [640,512] bf16 = 640 KB
    ushort_t* w_outT  = (ushort_t*)(ws + (122ull << 20));    // [512,128]
    ushort_t* w1T     = (ushort_t*)(ws + (123ull << 20));    // [2048,512] (2 MB)
    ushort_t* w2T     = (ushort_t*)(ws + (125ull << 20));    // [512,2048] (2 MB)
    float*    kern    = (float*)   (ws + (127ull << 20));    // 24 KB

    // MLP hidden chunk: prefer tail of ws; else reuse dead xn region (32 MB)
    size_t base = 128ull << 20;
    ushort_t* hid;
    int CC;
    if (ws_size >= base + ((size_t)Mrows * 2048 * 2)) { hid = (ushort_t*)(ws + base); CC = 2048; }
    else if (ws_size >= base + ((size_t)Mrows * 1024 * 2)) { hid = (ushort_t*)(ws + base); CC = 1024; }
    else { hid = (ushort_t*)ws; CC = 512; }   // xn is dead by MLP time
    int nch = MLPD / CC;

    dim3 blk(256);
    // weight transpose+convert. w_in and w_gate land adjacently in w_comb [640,512].
    convert_transpose<<<dim3(K2 / 32, Dd / 32), blk, 0, stream>>>(w_in, w_comb, Dd, K2);
    convert_transpose<<<dim3(Dd / 32, Dd / 32), blk, 0, stream>>>(w_gate, w_comb + (size_t)K2 * Dd, Dd, Dd);
    convert_transpose<<<dim3(Dd / 32, K2 / 32), blk, 0, stream>>>(w_out, w_outT, K2, Dd);
    convert_transpose<<<dim3(MLPD / 32, Dd / 32), blk, 0, stream>>>(w1, w1T, Dd, MLPD);
    convert_transpose<<<dim3(Dd / 32, MLPD / 32), blk, 0, stream>>>(w2, w2T, MLPD, Dd);
    kern_precompute<<<dim3((CW * Kk + 255) / 256), blk, 0, stream>>>(log_decay, frequency, kern);

    // xn = LN(x) -> bf16
    ln_bf_kernel<<<dim3(Mrows / 4), blk, 0, stream>>>(x, g1, bn1, xn);
    // fused: [beta | gate] = xn @ [w_in | w_gate]  (N=640)
    mfma_gemm<EPI_INCOMB><<<dim3(640 / 128, Mrows / 128), blk, 0, stream>>>(
        xn, w_comb, beta, gateb, Dd, Dd, 0, b_gate, nullptr, nullptr);
    // eigenstates: windowed conv + coupling -> eig (fp32 out) + eigb (bf16)
    conv_kernel<<<dim3(Tt / CT, Bb), blk, 0, stream>>>(beta, kern, coupling, eig, eigb);
    // x1 = x + gate * (eig @ w_out)  -> d_out[0:64MB]
    mfma_gemm<EPI_X1><<<dim3(Dd / 128, Mrows / 128), blk, 0, stream>>>(
        eigb, w_outT, out, nullptr, K2, K2, Dd, nullptr, x, gateb);
    // xn2 = LN(x1) -> bf16
    ln_bf_kernel<<<dim3(Mrows / 4), blk, 0, stream>>>(out, g2, bn2, xn2);
    // MLP: out = x1 + b2 + sum_c silu(xn2@w1_c + b1_c)@w2_c
    for (int c = 0; c < nch; c++) {
        mfma_gemm<EPI_SILU><<<dim3(CC / 128, Mrows / 128), blk, 0, stream>>>(
            xn2, w1T + (size_t)c * CC * Dd, hid, nullptr, Dd, Dd, CC, b1 + (size_t)c * CC, nullptr, nullptr);
        if (c == 0) {
            mfma_gemm<EPI_OUT0><<<dim3(Dd / 128, Mrows / 128), blk, 0, stream>>>(
                hid, w2T + (size_t)c * CC, out, nullptr, CC, MLPD, Dd, b2, nullptr, nullptr);
        } else {
            mfma_gemm<EPI_OUTA><<<dim3(Dd / 128, Mrows / 128), blk, 0, stream>>>(
                hid, w2T + (size_t)c * CC, out, nullptr, CC, MLPD, Dd, nullptr, nullptr, nullptr);
        }
    }
}

// Round 4
// 569.857 us; speedup vs baseline: 4.5746x; 1.0396x over previous
//
#include <hip/hip_runtime.h>
#include <math.h>
#include <stdint.h>

// Problem constants (fixed shapes per reference)
#define Bb   32
#define Tt   1024
#define Dd   512
#define Kk   64
#define K2   128     // 2K
#define Hh   4
#define KP   16
#define MLPD 2048
#define Mrows (Bb * Tt)   // 32768

// Conv window: mag <= sigmoid(-0.1)=0.475; 0.475^48 ~ 3e-16 -> exact to fp32
#define CW 48
#define CT 64

typedef unsigned short ushort_t;
typedef __attribute__((ext_vector_type(8))) short short8;     // 8 bf16 = 4 VGPRs
typedef __attribute__((ext_vector_type(4))) float floatx4;    // MFMA C/D

__device__ __forceinline__ float sigf(float x) { return 1.0f / (1.0f + __expf(-x)); }

__device__ __forceinline__ ushort_t f2bf(float f) {
    unsigned u = __float_as_uint(f);
    u += 0x7fffu + ((u >> 16) & 1u);   // round-to-nearest-even
    return (ushort_t)(u >> 16);
}
__device__ __forceinline__ float bf2f(ushort_t h) {
    return __uint_as_float(((unsigned)h) << 16);
}

// async global->LDS, 16B per lane. LDS dest is wave-uniform base + lane*16.
__device__ __forceinline__ void async16(const void* g, void* l) {
    __builtin_amdgcn_global_load_lds((const __attribute__((address_space(1))) void*)g,
                                     (__attribute__((address_space(3))) void*)l, 16, 0, 0);
}

// ---------------- LayerNorm: one wave per row of 512, bf16 output ----------------
__global__ __launch_bounds__(256) void ln_bf_kernel(const float* __restrict__ x,
                                                    const float* __restrict__ g,
                                                    const float* __restrict__ b,
                                                    ushort_t* __restrict__ o) {
    int row  = blockIdx.x * 4 + (threadIdx.x >> 6);
    int lane = threadIdx.x & 63;
    const float4* xr = (const float4*)(x + (size_t)row * Dd);
    float4 a = xr[lane];
    float4 c = xr[lane + 64];
    float s = a.x + a.y + a.z + a.w + c.x + c.y + c.z + c.w;
    float q = a.x * a.x + a.y * a.y + a.z * a.z + a.w * a.w
            + c.x * c.x + c.y * c.y + c.z * c.z + c.w * c.w;
#pragma unroll
    for (int m = 32; m > 0; m >>= 1) {
        s += __shfl_xor(s, m);
        q += __shfl_xor(q, m);
    }
    float mean = s * (1.0f / Dd);
    float var  = q * (1.0f / Dd) - mean * mean;
    float rs   = rsqrtf(var + 1e-5f);
    const float4* gg = (const float4*)g;
    const float4* bb = (const float4*)b;
    float4 g0 = gg[lane], g1 = gg[lane + 64];
    float4 b0 = bb[lane], b1 = bb[lane + 64];
    ushort4 r0, r1;
    r0.x = f2bf((a.x - mean) * rs * g0.x + b0.x);
    r0.y = f2bf((a.y - mean) * rs * g0.y + b0.y);
    r0.z = f2bf((a.z - mean) * rs * g0.z + b0.z);
    r0.w = f2bf((a.w - mean) * rs * g0.w + b0.w);
    r1.x = f2bf((c.x - mean) * rs * g1.x + b1.x);
    r1.y = f2bf((c.y - mean) * rs * g1.y + b1.y);
    r1.z = f2bf((c.z - mean) * rs * g1.z + b1.z);
    r1.w = f2bf((c.w - mean) * rs * g1.w + b1.w);
    ushort4* oo = (ushort4*)(o + (size_t)row * Dd);
    oo[lane]      = r0;
    oo[lane + 64] = r1;
}

// ---------------- fp32 [R,C] -> bf16 [C,R] transpose+convert ----------------
__global__ __launch_bounds__(256) void convert_transpose(const float* __restrict__ in,
                                                         ushort_t* __restrict__ out,
                                                         int R, int C) {
    __shared__ float t[32][33];
    int bx = blockIdx.x * 32;   // C offset
    int by = blockIdx.y * 32;   // R offset
    int tc = threadIdx.x & 31, tr = threadIdx.x >> 5;   // 8 rows per pass
#pragma unroll
    for (int i = 0; i < 4; i++)
        t[tr + 8 * i][tc] = in[(size_t)(by + tr + 8 * i) * C + bx + tc];
    __syncthreads();
#pragma unroll
    for (int i = 0; i < 4; i++)
        out[(size_t)(bx + tr + 8 * i) * R + by + tc] = f2bf(t[tc][tr + 8 * i]);
}

// ---------------- Kernel table precompute: kern[d][0..63]=real, [64..127]=imag ----
__global__ void kern_precompute(const float* __restrict__ log_decay,
                                const float* __restrict__ freq,
                                float* __restrict__ kern) {
    int i = blockIdx.x * 256 + threadIdx.x;
    if (i >= CW * Kk) return;
    int d = i >> 6, k = i & 63;
    float mag = 1.0f / (1.0f + expf(-log_decay[k]));
    float mp  = powf(mag, (float)d);
    float ph  = (float)d * freq[k];
    kern[d * K2 + k]      = mp * cosf(ph);
    kern[d * K2 + 64 + k] = mp * sinf(ph);
}

// ---------------- Windowed causal complex conv + per-head coupling ----------------
__global__ __launch_bounds__(256) void conv_kernel(const float* __restrict__ beta,
                                                   const float* __restrict__ kern,
                                                   const float* __restrict__ coup,
                                                   float* __restrict__ eig,
                                                   ushort_t* __restrict__ eigb) {
    __shared__ float sBeta[CT + CW][K2];   // 56 KB
    __shared__ float sCoup[Hh][KP][KP];    // transposed: [h][k][j]
    int b   = blockIdx.y;
    int t0  = blockIdx.x * CT;
    int tid = threadIdx.x;
    for (int i = tid; i < Hh * KP * KP; i += 256) {
        int h = i >> 8, j = (i >> 4) & 15, kk = i & 15;
        sCoup[h][kk][j] = coup[i];
    }
    for (int i = tid; i < (CT + CW) * K2; i += 256) {
        int r = i >> 7, c = i & 127;
        int t = t0 - CW + r;
        sBeta[r][c] = (t >= 0) ? beta[((size_t)b * Tt + t) * K2 + c] : 0.0f;
    }
    __syncthreads();
    int k  = tid & 63;
    int ts = tid >> 6;
    float cr[16], ci[16];
#pragma unroll
    for (int i = 0; i < 16; i++) { cr[i] = 0.0f; ci[i] = 0.0f; }
    for (int d = 0; d < CW; d++) {
        float kr = kern[d * K2 + k];
        float ki = kern[d * K2 + 64 + k];
#pragma unroll
        for (int i = 0; i < 16; i++) {
            int r    = CW + ts + 4 * i - d;
            float br = sBeta[r][k];
            float bi = sBeta[r][64 + k];
            cr[i] += kr * br - ki * bi;
            ci[i] += kr * bi + ki * br;
        }
    }
    __syncthreads();
#pragma unroll
    for (int i = 0; i < 16; i++) {
        int tl = ts + 4 * i;
        sBeta[tl][k]      = cr[i];
        sBeta[tl][64 + k] = ci[i];
    }
    __syncthreads();
    int h = k >> 4, jj = k & 15;
#pragma unroll
    for (int i = 0; i < 16; i++) {
        int tl = ts + 4 * i;
        float er = 0.0f, ei = 0.0f;
#pragma unroll
        for (int kk = 0; kk < KP; kk++) {
            float w = sCoup[h][kk][jj];
            er += w * sBeta[tl][h * KP + kk];
            ei += w * sBeta[tl][64 + h * KP + kk];
        }
        size_t off = ((size_t)b * Tt + t0 + tl) * K2;
        eig[off + k]       = er;
        eig[off + 64 + k]  = ei;
        eigb[off + k]      = f2bf(er);
        eigb[off + 64 + k] = f2bf(ei);
    }
}

// ---------------- bf16 MFMA GEMM, double-buffered async staging ----------------
// 128x128 tile, BK=32, 256 threads (4 waves, each 64x64 = 4x4 of 16x16x32 MFMA).
// LDS: 2 stages x (8 KB A + 8 KB B), prefetch 1 step ahead.
// Grid is 1-D, XCD-swizzled: all N-blocks of one A-strip share lin%8, so with
// round-robin workgroup->XCD dispatch they land on the SAME XCD and the A-strip
// is fetched into that XCD's L2 once (then L2-hit, ~200cyc, covered by prefetch).
// Swizzle of LDS colgroups: p = (g + (row>>1)) & 3 applied on global source addr.
enum { EPI_INCOMB = 0, EPI_X1, EPI_SILU, EPI_OUT0, EPI_OUTA };

#define STG 16384

template <int EPI>
__global__ __launch_bounds__(256) void mfma_gemm(
    const ushort_t* __restrict__ A, const ushort_t* __restrict__ Bt,
    void* __restrict__ Cv, void* __restrict__ Cv2, int K, int ldb, int ldc,
    int gx,
    const float* __restrict__ bias,
    const float* __restrict__ aux1, const ushort_t* __restrict__ aux2) {
    __shared__ __align__(16) char lds[2 * STG];
    int tid  = threadIdx.x;
    int lane = tid & 63, w = tid >> 6;
    // XCD-aware decode (M-block count must be divisible by 8; 256 is)
    int lin  = blockIdx.x;
    int xcd  = lin & 7;
    int rest = lin >> 3;
    int bx   = rest % gx;
    int by   = xcd + 8 * (rest / gx);
    int bm = by * 128, bn = bx * 128;
    int wm = (w >> 1) * 64, wn = (w & 1) * 64;

    // staging: each wave DMAs 2 A-chunks + 2 B-chunks of 1 KB (64 lanes x 16 B)
    const char* gA[2];
    const char* gB[2];
    int lofsA[2], lofsB[2];
#pragma unroll
    for (int q = 0; q < 2; q++) {
        int c = 2 * w + q;
        int m = c * 16 + (lane >> 2);                 // tile row this lane feeds
        int g = ((lane & 3) - ((m >> 1) & 3)) & 3;    // logical k-colgroup (swizzle)
        gA[q] = (const char*)(A  + (size_t)(bm + m) * K   + g * 8);
        gB[q] = (const char*)(Bt + (size_t)(bn + m) * ldb + g * 8);
        lofsA[q] = c * 1024;
        lofsB[q] = 8192 + c * 1024;
    }
    // fragment LDS byte offsets (swizzle-aware), fixed across K loop
    int aoff[4], boff[4];
#pragma unroll
    for (int i = 0; i < 4; i++) {
        int m = wm + i * 16 + (lane & 15);
        aoff[i] = m * 64 + ((((lane >> 4) + (m >> 1)) & 3) * 16);
        int n = wn + i * 16 + (lane & 15);
        boff[i] = 8192 + n * 64 + ((((lane >> 4) + (n >> 1)) & 3) * 16);
    }
    floatx4 acc[4][4];
#pragma unroll
    for (int i = 0; i < 4; i++)
#pragma unroll
        for (int j = 0; j < 4; j++) acc[i][j] = (floatx4)0.0f;

    // preload K-step 0 into stage 0
    async16(gA[0], lds + lofsA[0]);
    async16(gA[1], lds + lofsA[1]);
    async16(gB[0], lds + lofsB[0]);
    async16(gB[1], lds + lofsB[1]);
    __syncthreads();

    int p = 0;
    for (int k0 = 0; k0 < K; k0 += 32) {
        if (k0 + 32 < K) {   // prefetch next step into idle stage
            size_t kb = (size_t)(k0 + 32) * 2;
            char* d = lds + (p ^ 1) * STG;
            async16(gA[0] + kb, d + lofsA[0]);
            async16(gA[1] + kb, d + lofsA[1]);
            async16(gB[0] + kb, d + lofsB[0]);
            async16(gB[1] + kb, d + lofsB[1]);
        }
        const char* s = lds + p * STG;
        short8 af[4], bfr[4];
#pragma unroll
        for (int i = 0; i < 4; i++) af[i]  = *(const short8*)(s + aoff[i]);
#pragma unroll
        for (int j = 0; j < 4; j++) bfr[j] = *(const short8*)(s + boff[j]);
#pragma unroll
        for (int i = 0; i < 4; i++)
#pragma unroll
            for (int j = 0; j < 4; j++)
                acc[i][j] = __builtin_amdgcn_mfma_f32_16x16x32_bf16(af[i], bfr[j], acc[i][j], 0, 0, 0);
        __syncthreads();   // drains prefetch vmcnt + protects stage p for refill
        p ^= 1;
    }
    // epilogue: C/D layout col=lane&15, row=(lane>>4)*4+reg
    int rq = (lane >> 4) * 4;
    int cn = lane & 15;
#pragma unroll
    for (int i = 0; i < 4; i++) {
#pragma unroll
        for (int j = 0; j < 4; j++) {
            int col = bn + wn + j * 16 + cn;
#pragma unroll
            for (int r = 0; r < 4; r++) {
                int row    = bm + wm + i * 16 + rq + r;
                float v    = acc[i][j][r];
                if (EPI == EPI_INCOMB) {
                    // cols 0..127 -> beta fp32 [M,128]; cols 128..639 -> gate bf16 [M,512]
                    if (bx == 0) {
                        ((float*)Cv)[(size_t)row * K2 + col] = v;
                    } else {
                        int gc = col - 128;
                        ((ushort_t*)Cv2)[(size_t)row * Dd + gc] = f2bf(sigf(v + bias[gc]));
                    }
                } else if (EPI == EPI_X1) {
                    size_t off = (size_t)row * ldc + col;
                    ((float*)Cv)[off] = aux1[off] + bf2f(aux2[off]) * v;
                } else if (EPI == EPI_SILU) {
                    size_t off = (size_t)row * ldc + col;
                    float t = v + bias[col];
                    ((ushort_t*)Cv)[off] = f2bf(t * sigf(t));
                } else if (EPI == EPI_OUT0) {
                    size_t off = (size_t)row * ldc + col;
                    float* C = (float*)Cv;
                    C[off] = C[off] + v + bias[col];   // C holds x1; adds b2
                } else {  // EPI_OUTA
                    size_t off = (size_t)row * ldc + col;
                    ((float*)Cv)[off] += v;
                }
            }
        }
    }
}

extern "C" void kernel_launch(void* const* d_in, const int* in_sizes, int n_in,
                              void* d_out, int out_size, void* d_ws, size_t ws_size,
                              hipStream_t stream) {
    (void)in_sizes; (void)n_in; (void)out_size;
    const float* x         = (const float*)d_in[0];
    const float* w_in      = (const float*)d_in[1];
    const float* log_decay = (const float*)d_in[2];
    const float* frequency = (const float*)d_in[3];
    const float* coupling  = (const float*)d_in[4];
    const float* w_out     = (const float*)d_in[5];
    const float* w_gate    = (const float*)d_in[6];
    const float* b_gate    = (const float*)d_in[7];
    const float* w1        = (const float*)d_in[8];
    const float* b1        = (const float*)d_in[9];
    const float* w2        = (const float*)d_in[10];
    const float* b2        = (const float*)d_in[11];
    const float* g1        = (const float*)d_in[12];
    const float* bn1       = (const float*)d_in[13];
    const float* g2        = (const float*)d_in[14];
    const float* bn2       = (const float*)d_in[15];

    float* out = (float*)d_out;                        // [32768,512]; holds x1 then final
    float* eig = (float*)d_out + (size_t)Mrows * Dd;   // [32768,128] fp32 output

    // ws layout (MB offsets)
    char* ws = (char*)d_ws;
    ushort_t* xn      = (ushort_t*)(ws);                     // 32 MB  [M,512] bf16
    ushort_t* xn2     = (ushort_t*)(ws + (32ull  << 20));    // 32 MB
    float*    beta    = (float*)   (ws + (64ull  << 20));    // 16 MB  [M,128] fp32
    ushort_t* eigb    = (ushort_t*)(ws + (80ull  << 20));    //  8 MB  [M,128] bf16
    ushort_t* gateb   = (ushort_t*)(ws + (88ull  << 20));    // 32 MB  [M,512] bf16
    ushort_t* w_comb  = (ushort_t*)(ws + (120ull << 20));    // [640,512] bf16 = 640 KB
    ushort_t* w_outT  = (ushort_t*)(ws + (122ull << 20));    // [512,128]
    ushort_t* w1T     = (ushort_t*)(ws + (123ull << 20));    // [2048,512] (2 MB)
    ushort_t* w2T     = (ushort_t*)(ws + (125ull << 20));    // [512,2048] (2 MB)
    float*    kern    = (float*)   (ws + (127ull << 20));    // 24 KB

    // MLP hidden chunk: prefer tail of ws; else reuse dead xn region (32 MB)
    size_t base = 128ull << 20;
    ushort_t* hid;
    int CC;
    if (ws_size >= base + ((size_t)Mrows * 2048 * 2)) { hid = (ushort_t*)(ws + base); CC = 2048; }
    else if (ws_size >= base + ((size_t)Mrows * 1024 * 2)) { hid = (ushort_t*)(ws + base); CC = 1024; }
    else { hid = (ushort_t*)ws; CC = 512; }   // xn is dead by MLP time
    int nch = MLPD / CC;

    dim3 blk(256);
    // weight transpose+convert. w_in and w_gate land adjacently in w_comb [640,512].
    convert_transpose<<<dim3(K2 / 32, Dd / 32), blk, 0, stream>>>(w_in, w_comb, Dd, K2);
    convert_transpose<<<dim3(Dd / 32, Dd / 32), blk, 0, stream>>>(w_gate, w_comb + (size_t)K2 * Dd, Dd, Dd);
    convert_transpose<<<dim3(Dd / 32, K2 / 32), blk, 0, stream>>>(w_out, w_outT, K2, Dd);
    convert_transpose<<<dim3(MLPD / 32, Dd / 32), blk, 0, stream>>>(w1, w1T, Dd, MLPD);
    convert_transpose<<<dim3(Dd / 32, MLPD / 32), blk, 0, stream>>>(w2, w2T, MLPD, Dd);
    kern_precompute<<<dim3((CW * Kk + 255) / 256), blk, 0, stream>>>(log_decay, frequency, kern);

    // xn = LN(x) -> bf16
    ln_bf_kernel<<<dim3(Mrows / 4), blk, 0, stream>>>(x, g1, bn1, xn);
    // fused: [beta | gate] = xn @ [w_in | w_gate]  (N=640), XCD-swizzled 1-D grid
    mfma_gemm<EPI_INCOMB><<<dim3(5 * 256), blk, 0, stream>>>(
        xn, w_comb, beta, gateb, Dd, Dd, 0, 5, b_gate, nullptr, nullptr);
    // eigenstates: windowed conv + coupling -> eig (fp32 out) + eigb (bf16)
    conv_kernel<<<dim3(Tt / CT, Bb), blk, 0, stream>>>(beta, kern, coupling, eig, eigb);
    // x1 = x + gate * (eig @ w_out)  -> d_out[0:64MB]
    mfma_gemm<EPI_X1><<<dim3(4 * 256), blk, 0, stream>>>(
        eigb, w_outT, out, nullptr, K2, K2, Dd, 4, nullptr, x, gateb);
    // xn2 = LN(x1) -> bf16
    ln_bf_kernel<<<dim3(Mrows / 4), blk, 0, stream>>>(out, g2, bn2, xn2);
    // MLP: out = x1 + b2 + sum_c silu(xn2@w1_c + b1_c)@w2_c
    for (int c = 0; c < nch; c++) {
        mfma_gemm<EPI_SILU><<<dim3((CC / 128) * 256), blk, 0, stream>>>(
            xn2, w1T + (size_t)c * CC * Dd, hid, nullptr, Dd, Dd, CC, CC / 128, b1 + (size_t)c * CC, nullptr, nullptr);
        if (c == 0) {
            mfma_gemm<EPI_OUT0><<<dim3(4 * 256), blk, 0, stream>>>(
                hid, w2T + (size_t)c * CC, out, nullptr, CC, MLPD, Dd, 4, b2, nullptr, nullptr);
        } else {
            mfma_gemm<EPI_OUTA><<<dim3(4 * 256), blk, 0, stream>>>(
                hid, w2T + (size_t)c * CC, out, nullptr, CC, MLPD, Dd, 4, nullptr, nullptr, nullptr);
        }
    }
}